// Round 1
// baseline (7438.097 us; speedup 1.0000x reference)
//
#include <hip/hip_runtime.h>
#include <hip/hip_cooperative_groups.h>

namespace cg = cooperative_groups;

#define NPTS   2048
#define NBATCH 8
#define NPROB  24     // 8 batches x {xy, xx, yy}
#define NITER  30
#define TPB    512
#define WPB    8      // waves per block

// eps = 0.05, log-domain Sinkhorn in log2 space.
constexpr float KSC = 28.853900817779268f;   // log2(e)/eps
constexpr float C1f = 0.38123094930796995f;  // eps*ln(2048)  (uniform log-weight folded out)
constexpr float C2f = 0.03465735902799726f;  // eps*ln(2)

__device__ __forceinline__ float fexp2(float x) { return __builtin_amdgcn_exp2f(x); }
__device__ __forceinline__ float flog2(float x) { return __builtin_amdgcn_logf(x); }
__device__ __forceinline__ float fsqrt(float x) { return __builtin_amdgcn_sqrtf(x); }

// One half-pass: out[u] = C1 - C2*(log2 sum_j 2^(K*phi_j - K*||U_u - V_j||))
__device__ __forceinline__ void half_pass(const float* __restrict__ U,
                                          const float* __restrict__ V,
                                          const float* __restrict__ phi,
                                          float* __restrict__ o,
                                          float4* sh, int tid, int lane,
                                          int gw0, int gstep)
{
    // stage V coords + scaled potential into LDS (32 KiB)
    for (int j = tid; j < NPTS; j += TPB) {
        float4 t;
        t.x = V[3 * j + 0];
        t.y = V[3 * j + 1];
        t.z = V[3 * j + 2];
        t.w = KSC * phi[j];
        sh[j] = t;
    }
    __syncthreads();

    for (int r = gw0; r < NPTS; r += gstep) {
        const float ux = U[3 * r + 0];
        const float uy = U[3 * r + 1];
        const float uz = U[3 * r + 2];
        float m = -3.0e38f, s = 0.0f;
        #pragma unroll
        for (int c = 0; c < 2; ++c) {
            float a[16];
            #pragma unroll
            for (int t = 0; t < 16; ++t) {
                float4 v = sh[(c * 16 + t) * 64 + lane];
                float dx = ux - v.x, dy = uy - v.y, dz = uz - v.z;
                float d2 = fmaf(dz, dz, fmaf(dy, dy, fmaf(dx, dx, 1e-12f)));
                a[t] = fmaf(-KSC, fsqrt(d2), v.w);
            }
            float cm = a[0];
            #pragma unroll
            for (int t = 1; t < 16; ++t) cm = fmaxf(cm, a[t]);
            const float nm = fmaxf(m, cm);
            float cs = 0.0f;
            #pragma unroll
            for (int t = 0; t < 16; ++t) cs += fexp2(a[t] - nm);
            s = fmaf(s, fexp2(m - nm), cs);
            m = nm;
        }
        // wave-wide LSE merge (64 lanes)
        #pragma unroll
        for (int off = 32; off > 0; off >>= 1) {
            float m2 = __shfl_xor(m, off);
            float s2 = __shfl_xor(s, off);
            float nm = fmaxf(m, m2);
            s = s * fexp2(m - nm) + s2 * fexp2(m2 - nm);
            m = nm;
        }
        if (lane == 0) o[r] = C1f - C2f * (m + flog2(s));
    }
}

__global__ __launch_bounds__(TPB, 4)
void sinkhorn_all(const float* __restrict__ xyz1,
                  const float* __restrict__ xyz2,
                  float* __restrict__ fg,
                  float* __restrict__ out)
{
    __shared__ float4 sh[NPTS];     // 32 KiB
    __shared__ double red[WPB];

    cg::grid_group grid = cg::this_grid();

    const int tid  = threadIdx.x;
    const int lane = tid & 63;
    const int warp = tid >> 6;
    const int bpp  = gridDim.x / NPROB;      // blocks per problem
    const int p    = blockIdx.x / bpp;
    const int lb   = blockIdx.x - p * bpp;
    const int b    = p / 3;
    const int k    = p - 3 * b;              // 0: xy, 1: xx, 2: yy

    const float* xb = xyz1 + (size_t)b * NPTS * 3;
    const float* yb = xyz2 + (size_t)b * NPTS * 3;
    float* fv = fg + (size_t)p * NPTS;
    float* gv = fg + (size_t)(NPROB + p) * NPTS;

    const int gw0   = lb * WPB + warp;
    const int gstep = bpp * WPB;

    // f-update: rows U_f, cols V_f (uses g). g-update: rows U_g, cols V_g (uses new f).
    const float* Uf = (k == 2) ? yb : xb;
    const float* Vf = (k == 1) ? xb : yb;
    const float* Ug = (k == 0) ? yb : ((k == 1) ? xb : yb);
    const float* Vg = (k == 2) ? yb : xb;

    for (int it = 0; it < NITER; ++it) {
        half_pass(Uf, Vf, gv, fv, sh, tid, lane, gw0, gstep);
        grid.sync();
        half_pass(Ug, Vg, fv, gv, sh, tid, lane, gw0, gstep);
        grid.sync();
    }

    // final: loss = sum_p w_k * (sum f_p + sum g_p) / (N*B), block 0 only (deterministic)
    if (blockIdx.x == 0) {
        double acc = 0.0;
        for (int idx = tid; idx < 2 * NPROB * NPTS; idx += TPB) {
            int rem = (idx < NPROB * NPTS) ? idx : idx - NPROB * NPTS;
            int pp  = rem >> 11;             // / 2048
            int kk  = pp % 3;
            float w = (kk == 0) ? 1.0f : -0.5f;
            acc += (double)fg[idx] * (double)w;
        }
        #pragma unroll
        for (int off = 32; off > 0; off >>= 1) acc += __shfl_xor(acc, off);
        if (lane == 0) red[warp] = acc;
        __syncthreads();
        if (warp == 0) {
            double v2 = (lane < WPB) ? red[lane] : 0.0;
            #pragma unroll
            for (int off = 32; off > 0; off >>= 1) v2 += __shfl_xor(v2, off);
            if (lane == 0) out[0] = (float)(v2 / (double)(NBATCH * NPTS));
        }
    }
}

extern "C" void kernel_launch(void* const* d_in, const int* in_sizes, int n_in,
                              void* d_out, int out_size, void* d_ws, size_t ws_size,
                              hipStream_t stream)
{
    const float* xyz1 = (const float*)d_in[0];
    const float* xyz2 = (const float*)d_in[1];
    float* out = (float*)d_out;
    float* fg  = (float*)d_ws;   // f[NPROB][NPTS] then g[NPROB][NPTS]

    // f0 = g0 = 0 (deterministic per call)
    hipMemsetAsync(fg, 0, (size_t)2 * NPROB * NPTS * sizeof(float), stream);

    int maxBlocksPerCU = 0;
    hipOccupancyMaxActiveBlocksPerMultiprocessor(&maxBlocksPerCU, sinkhorn_all, TPB, 0);
    if (maxBlocksPerCU < 1) maxBlocksPerCU = 1;
    int cap = maxBlocksPerCU * 256;          // 256 CUs
    int bpp = cap / NPROB;
    if (bpp > 21) bpp = 21;                  // 24*21 = 504 blocks (2/CU co-resident)
    if (bpp < 1) bpp = 1;
    int nblk = bpp * NPROB;

    void* args[] = { (void*)&xyz1, (void*)&xyz2, (void*)&fg, (void*)&out };
    hipLaunchCooperativeKernel((void*)sinkhorn_all, dim3(nblk), dim3(TPB), args, 0, stream);
}

// Round 2
// 5910.720 us; speedup vs baseline: 1.2584x; 1.2584x over previous
//
#include <hip/hip_runtime.h>
#include <hip/hip_cooperative_groups.h>

namespace cg = cooperative_groups;

#define NPTS   2048
#define NBATCH 8
#define NPROB  24     // 8 batches x {xy, xx, yy}
#define NITER  30
#define TPB    512
#define WPB    8      // waves per block

// eps = 0.05, log-domain Sinkhorn in log2 space.
constexpr float KSC = 28.853900817779268f;   // log2(e)/eps
constexpr float C1f = 0.38123094930796995f;  // eps*ln(2048)
constexpr float C2f = 0.03465735902799726f;  // eps*ln(2)

__device__ __forceinline__ float fexp2(float x) { return __builtin_amdgcn_exp2f(x); }
__device__ __forceinline__ float flog2(float x) { return __builtin_amdgcn_logf(x); }
__device__ __forceinline__ float fsqrt(float x) { return __builtin_amdgcn_sqrtf(x); }

// ---- per-problem barrier (arrive/epoch in device scratch, 256B per problem) ----
// All blocks of one problem sit on one XCD (problem = blockIdx % 24, 24 % 8 == 0),
// but agent-scope atomics keep this correct regardless of placement.
__device__ __forceinline__ void problem_barrier(unsigned* arrive, unsigned* epoch,
                                                unsigned phase, int nbpp, int tid)
{
    __syncthreads();   // all waves' stores drained (s_waitcnt before s_barrier)
    if (tid == 0) {
        unsigned old = __hip_atomic_fetch_add(arrive, 1u, __ATOMIC_ACQ_REL,
                                              __HIP_MEMORY_SCOPE_AGENT);
        if (old == (unsigned)(nbpp - 1)) {
            // last arriver: reset count, then publish epoch (release orders the reset)
            __hip_atomic_store(arrive, 0u, __ATOMIC_RELAXED, __HIP_MEMORY_SCOPE_AGENT);
            __hip_atomic_store(epoch, phase, __ATOMIC_RELEASE, __HIP_MEMORY_SCOPE_AGENT);
        } else {
            while (__hip_atomic_load(epoch, __ATOMIC_RELAXED,
                                     __HIP_MEMORY_SCOPE_AGENT) < phase) {
                __builtin_amdgcn_s_sleep(4);
            }
            __threadfence();   // agent-scope acquire: invalidate L1/L2 before phi reads
        }
    }
    __syncthreads();
}

// One half-pass: o[u] = C1 - C2*(log2 sum_j 2^(K*phi_j - K*||U_u - V_j||))
__device__ __forceinline__ void half_pass(const float* __restrict__ U,
                                          const float* __restrict__ V,
                                          const float* __restrict__ phi,
                                          float* __restrict__ o,
                                          float4* sh, int tid, int lane,
                                          int gw0, int gstep)
{
    for (int j = tid; j < NPTS; j += TPB) {
        float4 t;
        t.x = V[3 * j + 0];
        t.y = V[3 * j + 1];
        t.z = V[3 * j + 2];
        t.w = KSC * phi[j];
        sh[j] = t;
    }
    __syncthreads();

    for (int r = gw0; r < NPTS; r += gstep) {
        const float ux = U[3 * r + 0];
        const float uy = U[3 * r + 1];
        const float uz = U[3 * r + 2];
        float m = -3.0e38f, s = 0.0f;
        #pragma unroll
        for (int c = 0; c < 2; ++c) {
            float a[16];
            #pragma unroll
            for (int t = 0; t < 16; ++t) {
                float4 v = sh[(c * 16 + t) * 64 + lane];
                float dx = ux - v.x, dy = uy - v.y, dz = uz - v.z;
                float d2 = fmaf(dz, dz, fmaf(dy, dy, fmaf(dx, dx, 1e-12f)));
                a[t] = fmaf(-KSC, fsqrt(d2), v.w);
            }
            float cm = a[0];
            #pragma unroll
            for (int t = 1; t < 16; ++t) cm = fmaxf(cm, a[t]);
            const float nm = fmaxf(m, cm);
            float cs0 = 0.f, cs1 = 0.f, cs2 = 0.f, cs3 = 0.f;
            #pragma unroll
            for (int t = 0; t < 16; t += 4) {
                cs0 += fexp2(a[t + 0] - nm);
                cs1 += fexp2(a[t + 1] - nm);
                cs2 += fexp2(a[t + 2] - nm);
                cs3 += fexp2(a[t + 3] - nm);
            }
            s = fmaf(s, fexp2(m - nm), (cs0 + cs1) + (cs2 + cs3));
            m = nm;
        }
        #pragma unroll
        for (int off = 32; off > 0; off >>= 1) {
            float m2 = __shfl_xor(m, off);
            float s2 = __shfl_xor(s, off);
            float nm = fmaxf(m, m2);
            s = s * fexp2(m - nm) + s2 * fexp2(m2 - nm);
            m = nm;
        }
        if (lane == 0) o[r] = C1f - C2f * (m + flog2(s));
    }
}

__global__ __launch_bounds__(TPB, 4)
void sinkhorn_all(const float* __restrict__ xyz1,
                  const float* __restrict__ xyz2,
                  float* __restrict__ fg,
                  unsigned* __restrict__ bars,   // 64 uints (256B) per problem
                  float* __restrict__ out,
                  int nbpp)
{
    __shared__ float4 sh[NPTS];     // 32 KiB
    __shared__ double red[WPB];

    cg::grid_group grid = cg::this_grid();

    const int tid  = threadIdx.x;
    const int lane = tid & 63;
    const int warp = tid >> 6;
    const int p    = blockIdx.x % NPROB;     // stride-24 => one XCD per problem
    const int lb   = blockIdx.x / NPROB;
    const int b    = p / 3;
    const int k    = p - 3 * b;              // 0: xy, 1: xx, 2: yy

    const float* xb = xyz1 + (size_t)b * NPTS * 3;
    const float* yb = xyz2 + (size_t)b * NPTS * 3;
    float* fv = fg + (size_t)p * NPTS;
    float* gv = fg + (size_t)(NPROB + p) * NPTS;
    unsigned* arrive = bars + (size_t)p * 64;        // own 128B line
    unsigned* epoch  = bars + (size_t)p * 64 + 32;   // own 128B line

    const int gw0   = lb * WPB + warp;
    const int gstep = nbpp * WPB;

    const float* Uf = (k == 2) ? yb : xb;
    const float* Vf = (k == 1) ? xb : yb;
    const float* Ug = (k == 0) ? yb : ((k == 1) ? xb : yb);
    const float* Vg = (k == 2) ? yb : xb;

    for (int it = 0; it < NITER; ++it) {
        half_pass(Uf, Vf, gv, fv, sh, tid, lane, gw0, gstep);
        problem_barrier(arrive, epoch, (unsigned)(2 * it + 1), nbpp, tid);
        half_pass(Ug, Vg, fv, gv, sh, tid, lane, gw0, gstep);
        problem_barrier(arrive, epoch, (unsigned)(2 * it + 2), nbpp, tid);
    }

    grid.sync();   // single full sync before the deterministic final reduce

    if (blockIdx.x == 0) {
        double acc = 0.0;
        for (int idx = tid; idx < 2 * NPROB * NPTS; idx += TPB) {
            int rem = (idx < NPROB * NPTS) ? idx : idx - NPROB * NPTS;
            int pp  = rem >> 11;             // / 2048
            int kk  = pp % 3;
            float w = (kk == 0) ? 1.0f : -0.5f;
            acc += (double)fg[idx] * (double)w;
        }
        #pragma unroll
        for (int off = 32; off > 0; off >>= 1) acc += __shfl_xor(acc, off);
        if (lane == 0) red[warp] = acc;
        __syncthreads();
        if (warp == 0) {
            double v2 = (lane < WPB) ? red[lane] : 0.0;
            #pragma unroll
            for (int off = 32; off > 0; off >>= 1) v2 += __shfl_xor(v2, off);
            if (lane == 0) out[0] = (float)(v2 / (double)(NBATCH * NPTS));
        }
    }
}

extern "C" void kernel_launch(void* const* d_in, const int* in_sizes, int n_in,
                              void* d_out, int out_size, void* d_ws, size_t ws_size,
                              hipStream_t stream)
{
    const float* xyz1 = (const float*)d_in[0];
    const float* xyz2 = (const float*)d_in[1];
    float* out = (float*)d_out;
    float* fg  = (float*)d_ws;                               // 2*24*2048 floats
    unsigned* bars = (unsigned*)((char*)d_ws + (size_t)2 * NPROB * NPTS * sizeof(float));

    // zero f/g and barrier state (deterministic per call)
    hipMemsetAsync(d_ws, 0,
                   (size_t)2 * NPROB * NPTS * sizeof(float) + (size_t)NPROB * 64 * sizeof(unsigned),
                   stream);

    int maxBlocksPerCU = 0;
    hipOccupancyMaxActiveBlocksPerMultiprocessor(&maxBlocksPerCU, sinkhorn_all, TPB, 0);
    if (maxBlocksPerCU < 1) maxBlocksPerCU = 1;
    int cap = maxBlocksPerCU * 256;          // 256 CUs, cooperative co-residency bound
    int bpp = cap / NPROB;
    if (bpp > 32) bpp = 32;                  // 24*32 = 768 blocks, 3/CU, 8 rows/wave exact
    if (bpp < 1) bpp = 1;
    int nblk = bpp * NPROB;

    void* args[] = { (void*)&xyz1, (void*)&xyz2, (void*)&fg, (void*)&bars, (void*)&out, (void*)&bpp };
    hipLaunchCooperativeKernel((void*)sinkhorn_all, dim3(nblk), dim3(TPB), args, 0, stream);
}